// Round 9
// baseline (413.338 us; speedup 1.0000x reference)
//
#include <hip/hip_runtime.h>

// BilinearInterpolation: B=16, H=W=512, C=16, OUT_H=OUT_W=512, fp32.
// theta = [[s,0,tx],[0,s,ty]] per batch. x = 0.5*(s*x_lin[j]+tx+1)*W,
// y = 0.5*(s*y_lin[i]+ty+1)*H, x_lin/y_lin = linspace(-1,1,512).
// x0 = trunc-toward-zero (numpy astype int32 == C cast), x1 = x0+1,
// THEN clip to [0,511]; weights computed from clipped values (matches ref).
//
// V3b structure: one block per (batch, out-row, half-row of 256 px).
//  - The two source rows' x-window [xlo..xhi] (<= ~258 px, since s in [0,1))
//    is staged into LDS with coalesced float4 streams.
//  - The 4 bilinear taps per output quad become LDS reads (reuse ~4x2/s)
//    instead of scattered global gathers -> removes L2/L3 latency from the
//    inner loop.
//  - LDS bank swizzle: physical element = x*4 + (q ^ ((x>>1)&3)). Without it,
//    even-dx pixels of a wave share one bank-quad with distinct addresses
//    (8-way conflict at s~1, m136: 2.94x). Swizzle -> <=2-way (free).
//    Applied on BOTH staging writes and compute reads (same involution).
//  - XCD-aware bijective block swizzle: blocks sharing input rows (adjacent
//    i, both halves) land on the same XCD's L2. (16384 % 8 == 0.)
//  - Nontemporal output stores (via native ext_vector_type — HIP's float4
//    class is rejected by __builtin_nontemporal_store) keep the 268 MB write
//    stream from evicting staged input rows out of L2.

#define BH   512
#define BW   512
#define BC   16
#define NB   16
#define HALF 256          // output pixels per block
#define WMAX 264          // staged window capacity (worst case ~258 px)
#define NXCD 8

typedef float f32x4 __attribute__((ext_vector_type(4)));

// bijective within each pixel's 4 channel-quads; spreads bank-quads
__device__ __forceinline__ int swz(int x_local, int q) {
    return (x_local << 2) | (q ^ ((x_local >> 1) & 3));
}

__global__ __launch_bounds__(256) void bilerp_kernel(
    const float* __restrict__ X,
    const float* __restrict__ scale,
    const float* __restrict__ translate,
    float* __restrict__ out)
{
    // [row(y0/y1)][swz(px_local, q)] ; 2*264*4*16B = 33,792 B -> 4 blocks/CU
    __shared__ float4 lds[2][WMAX * 4];

    // ---- XCD-aware bijective swizzle (nwg = 16384, divisible by 8) ----
    const int nwg_per_xcd = (NB * BH * 2) / NXCD;          // 2048
    const int wid = (blockIdx.x % NXCD) * nwg_per_xcd + blockIdx.x / NXCD;

    const int b    = wid >> 10;         // / 1024
    const int i    = (wid >> 1) & 511;
    const int half = wid & 1;

    const float s  = scale[b];
    const float tx = translate[2 * b];
    const float ty = translate[2 * b + 1];

    // ---- Row-uniform y coordinate and weights ----
    const float yl = -1.0f + 2.0f * (float)i / 511.0f;
    const float y  = 0.5f * (s * yl + ty + 1.0f) * (float)BH;
    int y0 = (int)y;                 // trunc toward zero, matches astype(int32)
    int y1 = y0 + 1;
    y0 = min(max(y0, 0), BH - 1);
    y1 = min(max(y1, 0), BH - 1);
    const float wy1 = (float)y1 - y;  // (y1f - y)
    const float wy0 = y - (float)y0;  // (y - y0f)

    // ---- x-window for this half-row (x(j) monotone non-decr. in j, s>=0;
    //      trunc is monotone, so clipped x0/x1 of every j land in
    //      [xlo, xhi]) ----
    const int jbase = half * HALF;
    const float xl_f = -1.0f + 2.0f * (float)jbase / 511.0f;
    const float xl_e = -1.0f + 2.0f * (float)(jbase + HALF - 1) / 511.0f;
    const float x_f  = 0.5f * (s * xl_f + tx + 1.0f) * (float)BW;
    const float x_e  = 0.5f * (s * xl_e + tx + 1.0f) * (float)BW;
    const int x0_f = (int)x_f;
    const int x0_e = (int)x_e;
    const int mlo = min(x0_f, x0_e);
    const int mhi = max(x0_f, x0_e) + 1;
    const int xlo = min(max(mlo, 0), BW - 1);
    const int xhi = min(max(mhi, 0), BW - 1);
    int width = xhi - xlo + 1;
    if (width > WMAX) width = WMAX;   // safety net; unreachable for s in [0,1)

    // ---- Stage the two source rows' window into LDS (coalesced float4).
    //      Writes stay within each 4-element group (bank pattern unchanged,
    //      2-way = free), just permuted by swz(). ----
    const float4* __restrict__ Xb = (const float4*)(X + (size_t)b * BH * BW * BC);
    const float4* __restrict__ g0 = Xb + (size_t)y0 * (BW * (BC / 4)) + xlo * 4;
    const float4* __restrict__ g1 = Xb + (size_t)y1 * (BW * (BC / 4)) + xlo * 4;
    const int nf4 = width * 4;                       // <= 1056 float4 slots
    for (int t = threadIdx.x; t < nf4; t += 256) {
        const int dst = swz(t >> 2, t & 3);
        lds[0][dst] = g0[t];
        lds[1][dst] = g1[t];
    }
    __syncthreads();

    // ---- Compute: 4 iterations, quad-per-thread (stores stay coalesced) ----
    f32x4* __restrict__ orow =
        (f32x4*)out + (size_t)(b * BH + i) * (BW * (BC / 4));

    const int tid = threadIdx.x;
    const int q   = tid & 3;         // channel quad within pixel (0..3)
    const int p0  = tid >> 2;        // pixel within 64-px group

    #pragma unroll
    for (int k = 0; k < 4; ++k) {
        const int j = jbase + p0 + 64 * k;
        const float xl = -1.0f + 2.0f * (float)j / 511.0f;
        const float x  = 0.5f * (s * xl + tx + 1.0f) * (float)BW;
        int x0 = (int)x;
        int x1 = x0 + 1;
        x0 = min(max(x0, 0), BW - 1);
        x1 = min(max(x1, 0), BW - 1);
        const float wx1 = (float)x1 - x;
        const float wx0 = x - (float)x0;

        const float wa = wx1 * wy1;
        const float wb = wx1 * wy0;
        const float wc = wx0 * wy1;
        const float wd = wx0 * wy0;

        const int i0 = swz(x0 - xlo, q);
        const int i1 = swz(x1 - xlo, q);
        const float4 pa = lds[0][i0];
        const float4 pb = lds[1][i0];
        const float4 pc = lds[0][i1];
        const float4 pd = lds[1][i1];

        f32x4 o;
        o.x = wa * pa.x + wb * pb.x + wc * pc.x + wd * pd.x;
        o.y = wa * pa.y + wb * pb.y + wc * pc.y + wd * pd.y;
        o.z = wa * pa.z + wb * pb.z + wc * pc.z + wd * pd.z;
        o.w = wa * pa.w + wb * pb.w + wc * pc.w + wd * pd.w;

        __builtin_nontemporal_store(o, &orow[j * 4 + q]);
    }
}

extern "C" void kernel_launch(void* const* d_in, const int* in_sizes, int n_in,
                              void* d_out, int out_size, void* d_ws, size_t ws_size,
                              hipStream_t stream) {
    const float* X         = (const float*)d_in[0];
    const float* scale     = (const float*)d_in[1];
    const float* translate = (const float*)d_in[2];
    float* out             = (float*)d_out;

    dim3 grid(NB * BH * 2);   // 16384 blocks: (batch, out-row, half-row)
    dim3 block(256);
    bilerp_kernel<<<grid, block, 0, stream>>>(X, scale, translate, out);
}